// Round 5
// baseline (409.787 us; speedup 1.0000x reference)
//
#include <hip/hip_runtime.h>
#include <hip/hip_bf16.h>
#include <stdint.h>

// Problem constants
#define NND   100000      // nodes
#define NED   400000      // edges
#define KD    512         // DIN
#define ND    512         // DOUT
#define MPAD  100096      // 782 * 128
#define PDROP 0.1f
#define INV_KEEP (1.0f/0.9f)

#define BM   128
#define BKF  32           // K per step
#define NT   16           // 512/32 K-steps
#define ASTR 40           // padded A row stride in bf16 (80 B): bank = row*20 mod 32 -> max 2-way

typedef __attribute__((ext_vector_type(4))) float f32x4;
typedef __attribute__((ext_vector_type(8))) short short8;
typedef __attribute__((ext_vector_type(8))) unsigned short ushort8;

// ---- ws layout (bytes) ----
#define WT_OFF   102498304    // wt_bf16 [512][512]
#define HP_OFF   103022592    // hp_bf16 [MPAD][512]
#define DEG_OFF  205520896    // deg_u32 [NND]
#define DINV_OFF 205920896    // dinv_f32[NND]
#define OFFS_OFF 206320896    // offs_u32[NND] (CSR cursor -> ends)
#define SRCS_OFF 206720896    // srcs_i32[NED]
#define BSUM_OFF 208320896    // block sums

__device__ __forceinline__ unsigned short f2bf(float f) {
  unsigned int x = __float_as_uint(f);
  unsigned int r = (x + 0x7fffu + ((x >> 16) & 1u)) >> 16;
  return (unsigned short)r;
}
__device__ __forceinline__ float bf2f(unsigned short u) {
  return __uint_as_float(((unsigned int)u) << 16);
}

// ---------- prep: W^T to bf16 (blocks 0..1023) + degree count (blocks 1024..2586) ----------
__global__ void k_prep(const float* __restrict__ W, unsigned short* __restrict__ wt,
                       const int* __restrict__ ei, unsigned int* __restrict__ deg) {
  int bb = blockIdx.x;
  if (bb < 1024) {
    int idx = bb * 256 + threadIdx.x;        // idx = n*512 + k
    int n = idx >> 9, k = idx & 511;
    wt[idx] = f2bf(W[k * 512 + n]);
  } else {
    int e = (bb - 1024) * 256 + threadIdx.x;
    if (e < NED) atomicAdd(&deg[ei[NED + e]], 1u);   // col = destination
  }
}

// ---------- exclusive scan of deg -> offs (+ dinv fused) ----------
__global__ void k_scan1(const unsigned int* __restrict__ deg,
                        unsigned int* __restrict__ offs, unsigned int* __restrict__ bsum,
                        float* __restrict__ dinv) {
  __shared__ unsigned int s[256];
  int tid = threadIdx.x;
  int i = blockIdx.x * 256 + tid;
  unsigned int v = (i < NND) ? deg[i] : 0u;
  if (i < NND) dinv[i] = rsqrtf((float)(v + 1u));   // +1 self-loop
  s[tid] = v;
  __syncthreads();
  for (int d = 1; d < 256; d <<= 1) {
    unsigned int t = (tid >= d) ? s[tid - d] : 0u;
    __syncthreads();
    s[tid] += t;
    __syncthreads();
  }
  if (i < NND) offs[i] = s[tid] - v;
  if (tid == 255) bsum[blockIdx.x] = s[255];
}
__global__ void k_scan2(unsigned int* __restrict__ bsum) {   // 391 entries
  __shared__ unsigned int s[512];
  int t = threadIdx.x;
  unsigned int v = (t < 391) ? bsum[t] : 0u;
  s[t] = v;
  __syncthreads();
  for (int d = 1; d < 512; d <<= 1) {
    unsigned int u = (t >= d) ? s[t - d] : 0u;
    __syncthreads();
    s[t] += u;
    __syncthreads();
  }
  if (t < 391) bsum[t] = s[t] - v;
}
__global__ void k_scan3(const unsigned int* __restrict__ bsum, unsigned int* __restrict__ offs) {
  int i = blockIdx.x * 256 + threadIdx.x;
  if (i < NND) offs[i] += bsum[blockIdx.x];
}

// ---------- CSR fill: offs acts as cursor; afterwards offs[i] == end(i) ----------
__global__ void k_fill(const int* __restrict__ ei, unsigned int* __restrict__ offs,
                       int* __restrict__ srcs) {
  int e = blockIdx.x * 256 + threadIdx.x;
  if (e < NED) {
    int dst = ei[NED + e];
    unsigned int pos = atomicAdd(&offs[dst], 1u);
    srcs[pos] = ei[e];
  }
}

// ---------- fused dropout + bf16 MFMA GEMM: hp = dinv_row * (dropout(x) @ W) ----------
// BM=128 x BN=512 (A read once), BK=32, 512 thr = 8 waves (2M x 4N),
// per-wave 64x128 out = acc[4][8].
// A: f32 global->reg->dropout->ds_write into padded LDS (2-way max bank conflict).
// B: wt is 512 KB (L2-resident) -> lanes read fragments DIRECTLY from global, no LDS.
__launch_bounds__(512, 2)
__global__ void k_fused(const float* __restrict__ x, const float* __restrict__ dm,
                        const unsigned short* __restrict__ wt,
                        const float* __restrict__ dinv,
                        unsigned short* __restrict__ hp) {
  __shared__ unsigned short As[2][BM * ASTR];   // 10 KB each

  int t = threadIdx.x, wave = t >> 6, lane = t & 63;
  int wm = wave >> 2, wn = wave & 3;
  int mb = blockIdx.x * BM;

  // A staging: thread t -> row t>>2 (0..127), col slot (t&3)*8 (8 f32)
  int ar = t >> 2;
  int ac = (t & 3) * 8;
  bool arow_ok = (mb + ar) < NND;
  size_t arow = arow_ok ? (size_t)(mb + ar) : 0;
  const float* xp = x + arow * KD + ac;
  const float* mp = dm + arow * KD + ac;
  unsigned short* awr0 = &As[0][ar * ASTR + ac];
  unsigned short* awr1 = &As[1][ar * ASTR + ac];

  int fr = lane & 15;
  int koff = (lane >> 4) * 8;
  // B fragment base: row wn*128 + fr, k-col koff; b[n] at kt: + n*16*KD + kt*32
  const unsigned short* bp = wt + (size_t)(wn * 128 + fr) * KD + koff;

  f32x4 zero = {0.f, 0.f, 0.f, 0.f};
  f32x4 acc[4][8];
  #pragma unroll
  for (int m = 0; m < 4; ++m)
    #pragma unroll
    for (int n = 0; n < 8; ++n) acc[m][n] = zero;

  float4 xv0, xv1, mv0, mv1;

  // ---- prologue: stage A step 0 ----
  xv0 = *(const float4*)(xp);     xv1 = *(const float4*)(xp + 4);
  mv0 = *(const float4*)(mp);     mv1 = *(const float4*)(mp + 4);
  {
    ushort8 u;
    const float* xs = (const float*)&xv0; const float* ms = (const float*)&mv0;
    #pragma unroll
    for (int j = 0; j < 4; ++j) u[j] = (arow_ok && ms[j] >= PDROP) ? f2bf(xs[j] * INV_KEEP) : 0;
    xs = (const float*)&xv1; ms = (const float*)&mv1;
    #pragma unroll
    for (int j = 0; j < 4; ++j) u[4 + j] = (arow_ok && ms[j] >= PDROP) ? f2bf(xs[j] * INV_KEEP) : 0;
    *(ushort8*)awr0 = u;
  }
  __syncthreads();

  int cur = 0;
  for (int kt = 0; kt < NT; ++kt) {
    int k0n = (kt + 1) * BKF;
    if (kt + 1 < NT) {
      // issue next A-tile loads early; they drain into regs under this step's MFMAs
      xv0 = *(const float4*)(xp + k0n);     xv1 = *(const float4*)(xp + k0n + 4);
      mv0 = *(const float4*)(mp + k0n);     mv1 = *(const float4*)(mp + k0n + 4);
    }
    // B fragments direct from global (L2-hot)
    short8 b[8];
    #pragma unroll
    for (int n = 0; n < 8; ++n)
      b[n] = *(const short8*)(bp + (size_t)n * 16 * KD + kt * BKF);
    // A fragments from padded LDS
    short8 a[4];
    #pragma unroll
    for (int m = 0; m < 4; ++m)
      a[m] = *(const short8*)(&As[cur][(wm * 64 + m * 16 + fr) * ASTR + koff]);
    #pragma unroll
    for (int m = 0; m < 4; ++m)
      #pragma unroll
      for (int n = 0; n < 8; ++n)
        acc[m][n] = __builtin_amdgcn_mfma_f32_16x16x32_bf16(a[m], b[n], acc[m][n], 0, 0, 0);
    if (kt + 1 < NT) {
      ushort8 u;
      const float* xs = (const float*)&xv0; const float* ms = (const float*)&mv0;
      #pragma unroll
      for (int j = 0; j < 4; ++j) u[j] = (arow_ok && ms[j] >= PDROP) ? f2bf(xs[j] * INV_KEEP) : 0;
      xs = (const float*)&xv1; ms = (const float*)&mv1;
      #pragma unroll
      for (int j = 0; j < 4; ++j) u[4 + j] = (arow_ok && ms[j] >= PDROP) ? f2bf(xs[j] * INV_KEEP) : 0;
      *(ushort8*)((cur == 0) ? awr1 : awr0) = u;
    }
    __syncthreads();
    cur ^= 1;
  }

  // epilogue: C/D layout col=lane&15, row=(lane>>4)*4+j; scale by dinv[row]
  int c0 = wn * 128 + (lane & 15);
  #pragma unroll
  for (int m = 0; m < 4; ++m) {
    int grb = mb + wm * 64 + m * 16 + (lane >> 4) * 4;
    #pragma unroll
    for (int j = 0; j < 4; ++j) {
      int gr = grb + j;
      if (gr < NND) {
        float dv = dinv[gr];
        size_t ro = (size_t)gr * ND + c0;
        #pragma unroll
        for (int n = 0; n < 8; ++n)
          hp[ro + n * 16] = f2bf(acc[m][n][j] * dv);
      }
    }
  }
}

// ---------- gather-aggregate: one wave per node ----------
__global__ void k_aggregate(const unsigned int* __restrict__ ends,
                            const unsigned int* __restrict__ deg,
                            const int* __restrict__ srcs,
                            const unsigned short* __restrict__ hp,
                            const float* __restrict__ dinv,
                            const float* __restrict__ b,
                            float* __restrict__ out) {
  int node = blockIdx.x * 4 + (threadIdx.x >> 6);
  if (node >= NND) return;
  int lane = threadIdx.x & 63;
  int q = lane * 8;

  float acc[8];
  ushort8 hs = *(const ushort8*)(hp + (size_t)node * ND + q);   // self-loop
  #pragma unroll
  for (int j = 0; j < 8; ++j) acc[j] = bf2f(hs[j]);

  unsigned int d = deg[node];
  unsigned int end = ends[node];
  unsigned int beg = end - d;
  for (unsigned int e = beg; e < end; ++e) {
    int s = srcs[e];
    ushort8 hv = *(const ushort8*)(hp + (size_t)s * ND + q);
    #pragma unroll
    for (int j = 0; j < 8; ++j) acc[j] += bf2f(hv[j]);
  }

  float dv = dinv[node];
  float4 b0 = *(const float4*)(b + q);
  float4 b1 = *(const float4*)(b + q + 4);
  float4 o0, o1;
  o0.x = acc[0] * dv + b0.x; o0.y = acc[1] * dv + b0.y;
  o0.z = acc[2] * dv + b0.z; o0.w = acc[3] * dv + b0.w;
  o1.x = acc[4] * dv + b1.x; o1.y = acc[5] * dv + b1.y;
  o1.z = acc[6] * dv + b1.z; o1.w = acc[7] * dv + b1.w;
  float* op = out + (size_t)node * ND + q;
  *(float4*)op = o0;
  *(float4*)(op + 4) = o1;
}

extern "C" void kernel_launch(void* const* d_in, const int* in_sizes, int n_in,
                              void* d_out, int out_size, void* d_ws, size_t ws_size,
                              hipStream_t stream) {
  const float* x  = (const float*)d_in[0];
  const int*   ei = (const int*)d_in[1];     // int64 in reference -> int32 in harness
  const float* W  = (const float*)d_in[2];
  const float* b  = (const float*)d_in[3];
  const float* dm = (const float*)d_in[4];
  float* out = (float*)d_out;

  char* ws = (char*)d_ws;
  unsigned short* wt   = (unsigned short*)(ws + WT_OFF);
  unsigned short* hp   = (unsigned short*)(ws + HP_OFF);
  unsigned int*   deg  = (unsigned int*)(ws + DEG_OFF);
  float*          dinv = (float*)(ws + DINV_OFF);
  unsigned int*   offs = (unsigned int*)(ws + OFFS_OFF);
  int*            srcs = (int*)(ws + SRCS_OFF);
  unsigned int*   bsum = (unsigned int*)(ws + BSUM_OFF);

  hipMemsetAsync(deg, 0, NND * sizeof(unsigned int), stream);
  hipLaunchKernelGGL(k_prep,      dim3(2587),  dim3(256), 0, stream, W, wt, ei, deg);
  hipLaunchKernelGGL(k_scan1,     dim3(391),   dim3(256), 0, stream, deg, offs, bsum, dinv);
  hipLaunchKernelGGL(k_scan2,     dim3(1),     dim3(512), 0, stream, bsum);
  hipLaunchKernelGGL(k_scan3,     dim3(391),   dim3(256), 0, stream, bsum, offs);
  hipLaunchKernelGGL(k_fill,      dim3(1563),  dim3(256), 0, stream, ei, offs, srcs);
  hipLaunchKernelGGL(k_fused,     dim3(782),   dim3(512), 0, stream, x, dm, wt, dinv, hp);
  hipLaunchKernelGGL(k_aggregate, dim3(25000), dim3(256), 0, stream, offs, deg, srcs, hp, dinv, b, out);
}

// Round 6
// 322.924 us; speedup vs baseline: 1.2690x; 1.2690x over previous
//
#include <hip/hip_runtime.h>
#include <hip/hip_bf16.h>
#include <stdint.h>

// Problem constants
#define NND   100000      // nodes
#define NED   400000      // edges
#define KD    512         // DIN
#define ND    512         // DOUT
#define PDROP 0.1f
#define INV_KEEP (1.0f/0.9f)

#define BM   64           // rows per block (A read exactly once: BN = 512 full width)
#define BKF  32           // K per step
#define NT   16           // 512/32 K-steps
#define NBLK 1564         // 100096/64

typedef __attribute__((ext_vector_type(4))) float f32x4;
typedef __attribute__((ext_vector_type(8))) short short8;
typedef __attribute__((ext_vector_type(8))) unsigned short ushort8;

// ---- ws layout (bytes) ----
#define WT_OFF   102498304    // wts bf16, chunk-permuted W^T, 512 KB
#define HP_OFF   103022592    // hp_bf16 [MPAD][512]
#define DEG_OFF  205520896    // deg_u32 [NND]
#define DINV_OFF 205920896    // dinv_f32[NND]
#define OFFS_OFF 206320896    // offs_u32[NND] (CSR cursor -> ends)
#define SRCS_OFF 206720896    // srcs_i32[NED]
#define BSUM_OFF 208320896    // block sums

__device__ __forceinline__ unsigned short f2bf(float f) {
  unsigned int x = __float_as_uint(f);
  unsigned int r = (x + 0x7fffu + ((x >> 16) & 1u)) >> 16;
  return (unsigned short)r;
}
__device__ __forceinline__ float bf2f(unsigned short u) {
  return __uint_as_float(((unsigned int)u) << 16);
}
__device__ __forceinline__ void gload_lds16(const void* g, void* l) {
  __builtin_amdgcn_global_load_lds(
      (const __attribute__((address_space(1))) unsigned int*)g,
      (__attribute__((address_space(3))) unsigned int*)l,
      16, 0, 0);
}
// conflict-free chunk index for 16B chunk (row, g) — see round theory for proof
__device__ __forceinline__ int cfc(int row, int g) {
  return row * 4 + ((g + ((row >> 1) & 3)) & 3);
}

// ---------- prep: permuted W^T to bf16 (blocks 0..1023) + degree count ----------
// wts[idx]: idx = kt*16384 + c*8 + e ; chunk c holds (row = c>>2, g = ((c&3)-((row>>1)&3))&3)
// value = W[kt*32 + g*8 + e][row]  (B-row = output col n = "row")
__global__ void k_prep(const float* __restrict__ W, unsigned short* __restrict__ wts,
                       const int* __restrict__ ei, unsigned int* __restrict__ deg) {
  int bb = blockIdx.x;
  if (bb < 1024) {
    int idx = bb * 256 + threadIdx.x;        // 262144 total
    int kt = idx >> 14;
    int c  = (idx >> 3) & 2047;
    int e  = idx & 7;
    int row = c >> 2;
    int g = ((c & 3) - ((row >> 1) & 3)) & 3;
    int k = kt * 32 + g * 8 + e;
    wts[idx] = f2bf(W[(size_t)k * 512 + row]);
  } else {
    int e = (bb - 1024) * 256 + threadIdx.x;
    if (e < NED) atomicAdd(&deg[ei[NED + e]], 1u);   // col = destination
  }
}

// ---------- exclusive scan of deg -> offs (+ dinv fused) ----------
__global__ void k_scan1(const unsigned int* __restrict__ deg,
                        unsigned int* __restrict__ offs, unsigned int* __restrict__ bsum,
                        float* __restrict__ dinv) {
  __shared__ unsigned int s[256];
  int tid = threadIdx.x;
  int i = blockIdx.x * 256 + tid;
  unsigned int v = (i < NND) ? deg[i] : 0u;
  if (i < NND) dinv[i] = rsqrtf((float)(v + 1u));   // +1 self-loop
  s[tid] = v;
  __syncthreads();
  for (int d = 1; d < 256; d <<= 1) {
    unsigned int t = (tid >= d) ? s[tid - d] : 0u;
    __syncthreads();
    s[tid] += t;
    __syncthreads();
  }
  if (i < NND) offs[i] = s[tid] - v;
  if (tid == 255) bsum[blockIdx.x] = s[255];
}
__global__ void k_scan2(unsigned int* __restrict__ bsum) {   // 391 entries
  __shared__ unsigned int s[512];
  int t = threadIdx.x;
  unsigned int v = (t < 391) ? bsum[t] : 0u;
  s[t] = v;
  __syncthreads();
  for (int d = 1; d < 512; d <<= 1) {
    unsigned int u = (t >= d) ? s[t - d] : 0u;
    __syncthreads();
    s[t] += u;
    __syncthreads();
  }
  if (t < 391) bsum[t] = s[t] - v;
}
__global__ void k_scan3(const unsigned int* __restrict__ bsum, unsigned int* __restrict__ offs) {
  int i = blockIdx.x * 256 + threadIdx.x;
  if (i < NND) offs[i] += bsum[blockIdx.x];
}

// ---------- CSR fill ----------
__global__ void k_fill(const int* __restrict__ ei, unsigned int* __restrict__ offs,
                       int* __restrict__ srcs) {
  int e = blockIdx.x * 256 + threadIdx.x;
  if (e < NED) {
    int dst = ei[NED + e];
    unsigned int pos = atomicAdd(&offs[dst], 1u);
    srcs[pos] = ei[e];
  }
}

// ---------- fused dropout + bf16 MFMA GEMM: hp = dinv_row * (dropout(x) @ W) ----------
// BM=64 x BN=512, BK=32, 512 thr = 8 waves (2M x 4N), wave tile 32x128, acc[2][8].
// A: f32 global->reg->dropout->ds_write into conflict-free chunked LDS (4 KB).
// B: pre-permuted wts -> linear global_load_lds (32 KB), conflict-free chunked reads.
// Single-buffered, 2 barriers/step; A-regs for kt+1 prefetched under MFMA(kt).
__global__ void __launch_bounds__(512, 3)
k_fused(const float* __restrict__ x, const float* __restrict__ dm,
        const unsigned short* __restrict__ wts,
        const float* __restrict__ dinv,
        unsigned short* __restrict__ hp) {
  __shared__ unsigned short As[BM * BKF];     // 4 KB, chunked
  __shared__ unsigned short Bs[512 * BKF];    // 32 KB, chunked

  int t = threadIdx.x, wave = t >> 6, lane = t & 63;
  int wm = wave >> 2, wn = wave & 3;
  int mb = blockIdx.x * BM;

  // A staging: thread t -> row t>>3, 4 f32 at col (t&7)*4
  int ar = t >> 3;
  int ag = (t & 7) >> 1, ah = t & 1;
  bool arow_ok = (mb + ar) < NND;
  const float* xp = x + (size_t)(arow_ok ? mb + ar : 0) * KD + (t & 7) * 4;
  const float* mp = dm + (size_t)(arow_ok ? mb + ar : 0) * KD + (t & 7) * 4;
  char* awp = (char*)As + cfc(ar, ag) * 16 + ah * 8;

  int fr = lane & 15;
  int kg = lane >> 4;

  // precompute frag read pointers (single buffer -> loop-invariant)
  const short8* ap[2];
  #pragma unroll
  for (int m = 0; m < 2; ++m)
    ap[m] = (const short8*)((char*)As + cfc(wm * 32 + m * 16 + fr, kg) * 16);
  const short8* bpp[8];
  #pragma unroll
  for (int n = 0; n < 8; ++n)
    bpp[n] = (const short8*)((char*)Bs + cfc(wn * 128 + n * 16 + fr, kg) * 16);

  f32x4 zero = {0.f, 0.f, 0.f, 0.f};
  f32x4 acc[2][8];
  #pragma unroll
  for (int m = 0; m < 2; ++m)
    #pragma unroll
    for (int n = 0; n < 8; ++n) acc[m][n] = zero;

  // prologue: A regs for step 0
  float4 xv = *(const float4*)xp;
  float4 mv = *(const float4*)mp;

  for (int kt = 0; kt < NT; ++kt) {
    // ---- STAGE ----
    {
      ushort4 u;
      const float* xs = (const float*)&xv;
      const float* ms = (const float*)&mv;
      #pragma unroll
      for (int j = 0; j < 4; ++j)
        u[j] = (arow_ok && ms[j] >= PDROP) ? f2bf(xs[j] * INV_KEEP) : 0;
      *(ushort4*)awp = u;
    }
    #pragma unroll
    for (int i = 0; i < 4; ++i)
      gload_lds16(wts + (size_t)kt * 16384 + (i * 512 + t) * 8,
                  (char*)Bs + i * 8192 + t * 16);
    __syncthreads();
    // ---- COMPUTE ----
    if (kt + 1 < NT) {     // prefetch next A regs; latency hidden under MFMAs
      xv = *(const float4*)(xp + (kt + 1) * BKF);
      mv = *(const float4*)(mp + (kt + 1) * BKF);
    }
    short8 a[2], b[8];
    #pragma unroll
    for (int m = 0; m < 2; ++m) a[m] = *ap[m];
    #pragma unroll
    for (int n = 0; n < 8; ++n) b[n] = *bpp[n];
    #pragma unroll
    for (int m = 0; m < 2; ++m)
      #pragma unroll
      for (int n = 0; n < 8; ++n)
        acc[m][n] = __builtin_amdgcn_mfma_f32_16x16x32_bf16(a[m], b[n], acc[m][n], 0, 0, 0);
    __syncthreads();
  }

  // epilogue: C/D layout col=lane&15, row=(lane>>4)*4+j; scale by dinv[row]
  int c0 = wn * 128 + fr;
  #pragma unroll
  for (int m = 0; m < 2; ++m) {
    int grb = mb + wm * 32 + m * 16 + kg * 4;
    #pragma unroll
    for (int j = 0; j < 4; ++j) {
      int gr = grb + j;
      if (gr < NND) {
        float dv = dinv[gr];
        size_t ro = (size_t)gr * ND + c0;
        #pragma unroll
        for (int n = 0; n < 8; ++n)
          hp[ro + n * 16] = f2bf(acc[m][n][j] * dv);
      }
    }
  }
}

// ---------- gather-aggregate: one wave per node ----------
__global__ void k_aggregate(const unsigned int* __restrict__ ends,
                            const unsigned int* __restrict__ deg,
                            const int* __restrict__ srcs,
                            const unsigned short* __restrict__ hp,
                            const float* __restrict__ dinv,
                            const float* __restrict__ b,
                            float* __restrict__ out) {
  int node = blockIdx.x * 4 + (threadIdx.x >> 6);
  if (node >= NND) return;
  int lane = threadIdx.x & 63;
  int q = lane * 8;

  float acc[8];
  ushort8 hs = *(const ushort8*)(hp + (size_t)node * ND + q);   // self-loop
  #pragma unroll
  for (int j = 0; j < 8; ++j) acc[j] = bf2f(hs[j]);

  unsigned int d = deg[node];
  unsigned int end = ends[node];
  unsigned int beg = end - d;
  for (unsigned int e = beg; e < end; ++e) {
    int s = srcs[e];
    ushort8 hv = *(const ushort8*)(hp + (size_t)s * ND + q);
    #pragma unroll
    for (int j = 0; j < 8; ++j) acc[j] += bf2f(hv[j]);
  }

  float dv = dinv[node];
  float4 b0 = *(const float4*)(b + q);
  float4 b1 = *(const float4*)(b + q + 4);
  float4 o0, o1;
  o0.x = acc[0] * dv + b0.x; o0.y = acc[1] * dv + b0.y;
  o0.z = acc[2] * dv + b0.z; o0.w = acc[3] * dv + b0.w;
  o1.x = acc[4] * dv + b1.x; o1.y = acc[5] * dv + b1.y;
  o1.z = acc[6] * dv + b1.z; o1.w = acc[7] * dv + b1.w;
  float* op = out + (size_t)node * ND + q;
  *(float4*)op = o0;
  *(float4*)(op + 4) = o1;
}

extern "C" void kernel_launch(void* const* d_in, const int* in_sizes, int n_in,
                              void* d_out, int out_size, void* d_ws, size_t ws_size,
                              hipStream_t stream) {
  const float* x  = (const float*)d_in[0];
  const int*   ei = (const int*)d_in[1];     // int64 in reference -> int32 in harness
  const float* W  = (const float*)d_in[2];
  const float* b  = (const float*)d_in[3];
  const float* dm = (const float*)d_in[4];
  float* out = (float*)d_out;

  char* ws = (char*)d_ws;
  unsigned short* wts  = (unsigned short*)(ws + WT_OFF);
  unsigned short* hp   = (unsigned short*)(ws + HP_OFF);
  unsigned int*   deg  = (unsigned int*)(ws + DEG_OFF);
  float*          dinv = (float*)(ws + DINV_OFF);
  unsigned int*   offs = (unsigned int*)(ws + OFFS_OFF);
  int*            srcs = (int*)(ws + SRCS_OFF);
  unsigned int*   bsum = (unsigned int*)(ws + BSUM_OFF);

  hipMemsetAsync(deg, 0, NND * sizeof(unsigned int), stream);
  hipLaunchKernelGGL(k_prep,      dim3(2587),  dim3(256), 0, stream, W, wts, ei, deg);
  hipLaunchKernelGGL(k_scan1,     dim3(391),   dim3(256), 0, stream, deg, offs, bsum, dinv);
  hipLaunchKernelGGL(k_scan2,     dim3(1),     dim3(512), 0, stream, bsum);
  hipLaunchKernelGGL(k_scan3,     dim3(391),   dim3(256), 0, stream, bsum, offs);
  hipLaunchKernelGGL(k_fill,      dim3(1563),  dim3(256), 0, stream, ei, offs, srcs);
  hipLaunchKernelGGL(k_fused,     dim3(NBLK),  dim3(512), 0, stream, x, dm, wts, dinv, hp);
  hipLaunchKernelGGL(k_aggregate, dim3(25000), dim3(256), 0, stream, offs, deg, srcs, hp, dinv, b, out);
}

// Round 7
// 297.759 us; speedup vs baseline: 1.3762x; 1.0845x over previous
//
#include <hip/hip_runtime.h>
#include <hip/hip_bf16.h>
#include <stdint.h>

// Problem constants
#define NND   100000      // nodes
#define NED   400000      // edges
#define KD    512         // DIN
#define ND    512         // DOUT
#define PDROP 0.1f
#define INV_KEEP (1.0f/0.9f)

#define BM   64           // rows per block (A read exactly once: BN = 512 full width)
#define BKF  32           // K per step
#define NT   16           // 512/32 K-steps
#define NBLK 1564         // 100096/64

typedef __attribute__((ext_vector_type(4))) float f32x4;
typedef __attribute__((ext_vector_type(8))) short short8;
typedef __attribute__((ext_vector_type(8))) unsigned short ushort8;

// ---- ws layout (bytes) ----
#define WT_OFF   102498304    // wts bf16, chunk-permuted W^T, 512 KB
#define HP_OFF   103022592    // hp_bf16 [MPAD][512]
#define DEG_OFF  205520896    // deg_u32 [NND]
#define DINV_OFF 205920896    // dinv_f32[NND]
#define OFFS_OFF 206320896    // offs_u32[NND] (CSR cursor -> ends)
#define SRCS_OFF 206720896    // srcs_i32[NED]
#define BSUM_OFF 208320896    // block sums

#define SBAR()   __builtin_amdgcn_sched_barrier(0)
#define WAITV(N) asm volatile("s_waitcnt vmcnt(" #N ")" ::: "memory")
#define WAITL()  asm volatile("s_waitcnt lgkmcnt(0)" ::: "memory")

__device__ __forceinline__ unsigned short f2bf(float f) {
  unsigned int x = __float_as_uint(f);
  unsigned int r = (x + 0x7fffu + ((x >> 16) & 1u)) >> 16;
  return (unsigned short)r;
}
__device__ __forceinline__ float bf2f(unsigned short u) {
  return __uint_as_float(((unsigned int)u) << 16);
}
__device__ __forceinline__ void gload_lds16(const void* g, void* l) {
  __builtin_amdgcn_global_load_lds(
      (const __attribute__((address_space(1))) unsigned int*)g,
      (__attribute__((address_space(3))) unsigned int*)l,
      16, 0, 0);
}
// conflict-free chunk index for 16B chunk (row, g)
__device__ __forceinline__ int cfc(int row, int g) {
  return row * 4 + ((g + ((row >> 1) & 3)) & 3);
}

// ---------- prep: permuted W^T to bf16 (blocks 0..1023) + degree count ----------
// wts[idx]: idx = kt*16384 + c*8 + e ; chunk c holds (row = c>>2, g = ((c&3)-((row>>1)&3))&3)
// value = W[kt*32 + g*8 + e][row]
__global__ void k_prep(const float* __restrict__ W, unsigned short* __restrict__ wts,
                       const int* __restrict__ ei, unsigned int* __restrict__ deg) {
  int bb = blockIdx.x;
  if (bb < 1024) {
    int idx = bb * 256 + threadIdx.x;        // 262144 total
    int kt = idx >> 14;
    int c  = (idx >> 3) & 2047;
    int e  = idx & 7;
    int row = c >> 2;
    int g = ((c & 3) - ((row >> 1) & 3)) & 3;
    int k = kt * 32 + g * 8 + e;
    wts[idx] = f2bf(W[(size_t)k * 512 + row]);
  } else {
    int e = (bb - 1024) * 256 + threadIdx.x;
    if (e < NED) atomicAdd(&deg[ei[NED + e]], 1u);   // col = destination
  }
}

// ---------- exclusive scan of deg -> offs (+ dinv fused) ----------
__global__ void k_scan1(const unsigned int* __restrict__ deg,
                        unsigned int* __restrict__ offs, unsigned int* __restrict__ bsum,
                        float* __restrict__ dinv) {
  __shared__ unsigned int s[256];
  int tid = threadIdx.x;
  int i = blockIdx.x * 256 + tid;
  unsigned int v = (i < NND) ? deg[i] : 0u;
  if (i < NND) dinv[i] = rsqrtf((float)(v + 1u));   // +1 self-loop
  s[tid] = v;
  __syncthreads();
  for (int d = 1; d < 256; d <<= 1) {
    unsigned int t = (tid >= d) ? s[tid - d] : 0u;
    __syncthreads();
    s[tid] += t;
    __syncthreads();
  }
  if (i < NND) offs[i] = s[tid] - v;
  if (tid == 255) bsum[blockIdx.x] = s[255];
}
__global__ void k_scan2(unsigned int* __restrict__ bsum) {   // 391 entries
  __shared__ unsigned int s[512];
  int t = threadIdx.x;
  unsigned int v = (t < 391) ? bsum[t] : 0u;
  s[t] = v;
  __syncthreads();
  for (int d = 1; d < 512; d <<= 1) {
    unsigned int u = (t >= d) ? s[t - d] : 0u;
    __syncthreads();
    s[t] += u;
    __syncthreads();
  }
  if (t < 391) bsum[t] = s[t] - v;
}
__global__ void k_scan3(const unsigned int* __restrict__ bsum, unsigned int* __restrict__ offs) {
  int i = blockIdx.x * 256 + threadIdx.x;
  if (i < NND) offs[i] += bsum[blockIdx.x];
}

// ---------- CSR fill ----------
__global__ void k_fill(const int* __restrict__ ei, unsigned int* __restrict__ offs,
                       int* __restrict__ srcs) {
  int e = blockIdx.x * 256 + threadIdx.x;
  if (e < NED) {
    int dst = ei[NED + e];
    unsigned int pos = atomicAdd(&offs[dst], 1u);
    srcs[pos] = ei[e];
  }
}

// ---------- fused dropout + bf16 MFMA GEMM: hp = dinv_row * (dropout(x) @ W) ----------
// BM=64 x BN=512, BK=32, 512 thr = 8 waves (2M x 4N), wave tile 32x128, acc[2][8].
// Double-buffered As (2x4KB) + Bs (2x32KB) = 72 KB -> 2 blocks/CU.
// Software pipeline: compute(cur) || B(kt+1) in flight; stage kt+2 after barrier1.
// Raw s_barrier + counted waits (T3/T4); never drains vmcnt to 0 in steady state.
__global__ void __launch_bounds__(512, 4)
k_fused(const float* __restrict__ x, const float* __restrict__ dm,
        const unsigned short* __restrict__ wts,
        const float* __restrict__ dinv,
        unsigned short* __restrict__ hp) {
  __shared__ unsigned short As[2 * 2048];    // 2 x 4 KB, chunked
  __shared__ unsigned short Bs[2 * 16384];   // 2 x 32 KB, chunked

  const int t = threadIdx.x, wave = t >> 6, lane = t & 63;
  const int wm = wave >> 2, wn = wave & 3;
  const int mb = blockIdx.x * BM;

  // A staging: thread t -> row t>>3, 4 f32 at col (t&7)*4
  const int ar = t >> 3, ag = (t & 7) >> 1, ah = t & 1;
  const bool arow_ok = (mb + ar) < NND;
  const float* xp = x + (size_t)(arow_ok ? mb + ar : 0) * KD + (t & 7) * 4;
  const float* mp = dm + (size_t)(arow_ok ? mb + ar : 0) * KD + (t & 7) * 4;
  const int awoff = cfc(ar, ag) * 16 + ah * 8;   // byte offset within an As half

  const int fr = lane & 15, kg = lane >> 4;
  const int aoff0 = cfc(wm * 32 + fr, kg) * 16;
  const int aoff1 = cfc(wm * 32 + 16 + fr, kg) * 16;

  f32x4 zero = {0.f, 0.f, 0.f, 0.f};
  f32x4 acc[2][8];
  #pragma unroll
  for (int n = 0; n < 8; ++n) { acc[0][n] = zero; acc[1][n] = zero; }

  float4 xv, mv;

  // ---- prologue ----
  xv = *(const float4*)xp;  mv = *(const float4*)mp;      // tile 0 regs
  {  // B(0) -> Bs[0]
    #pragma unroll
    for (int i = 0; i < 4; ++i)
      gload_lds16(wts + (size_t)(i * 512 + t) * 8, (char*)Bs + i * 8192 + t * 16);
  }
  {  // consume tile0 regs -> As[0]  (auto vmcnt wait, B(0) may stay in flight)
    ushort4 u;
    const float* xs = (const float*)&xv; const float* ms = (const float*)&mv;
    #pragma unroll
    for (int j = 0; j < 4; ++j)
      u[j] = (arow_ok && ms[j] >= PDROP) ? f2bf(xs[j] * INV_KEEP) : 0;
    *(ushort4*)((char*)As + awoff) = u;
  }
  xv = *(const float4*)(xp + BKF);  mv = *(const float4*)(mp + BKF);  // tile 1 regs
  {  // B(1) -> Bs[1]
    #pragma unroll
    for (int i = 0; i < 4; ++i)
      gload_lds16(wts + (size_t)16384 + (i * 512 + t) * 8,
                  (char*)Bs + 32768 + i * 8192 + t * 16);
  }
  SBAR(); WAITV(6); WAITL(); SBAR();    // B(0) done, As[0] written
  __builtin_amdgcn_s_barrier();
  SBAR();

  // ---- main loop ----
  for (int kt = 0; kt < NT; ++kt) {
    const int cur = kt & 1;
    const char* ab = (const char*)As + cur * 4096;
    const char* bb = (const char*)Bs + cur * 32768;

    // compute phase: ds_read + MFMA (compiler interleaves, auto lgkm waits)
    short8 a0 = *(const short8*)(ab + aoff0);
    short8 a1 = *(const short8*)(ab + aoff1);
    #pragma unroll
    for (int n = 0; n < 8; ++n) {
      short8 b = *(const short8*)(bb + cfc(wn * 128 + n * 16 + fr, kg) * 16);
      acc[0][n] = __builtin_amdgcn_mfma_f32_16x16x32_bf16(a0, b, acc[0][n], 0, 0, 0);
      acc[1][n] = __builtin_amdgcn_mfma_f32_16x16x32_bf16(a1, b, acc[1][n], 0, 0, 0);
    }
    SBAR();
    __builtin_amdgcn_s_barrier();        // barrier 1: all waves done reading buf[cur]
    SBAR();

    // stage phase: tile kt+2 -> buf[cur]; A ds_write tile kt+1 -> buf[cur^1]
    if (kt < NT - 2) {                   // B(kt+2)
      const unsigned short* src = wts + (size_t)(kt + 2) * 16384;
      char* dst = (char*)Bs + cur * 32768;
      #pragma unroll
      for (int i = 0; i < 4; ++i)
        gload_lds16(src + (size_t)(i * 512 + t) * 8, dst + i * 8192 + t * 16);
    }
    if (kt < NT - 1) {                   // consume tile kt+1 regs (forces B(kt+1) retire via FIFO)
      ushort4 u;
      const float* xs = (const float*)&xv; const float* ms = (const float*)&mv;
      #pragma unroll
      for (int j = 0; j < 4; ++j)
        u[j] = (arow_ok && ms[j] >= PDROP) ? f2bf(xs[j] * INV_KEEP) : 0;
      *(ushort4*)((char*)As + (cur ^ 1) * 4096 + awoff) = u;
      if (kt < NT - 2) {                 // load tile kt+2 regs (consumed next iter)
        xv = *(const float4*)(xp + (kt + 2) * BKF);
        mv = *(const float4*)(mp + (kt + 2) * BKF);
      }
    }
    SBAR();
    if (kt < NT - 2) { WAITV(6); } else { WAITV(0); }
    WAITL();                             // ds_write visible before barrier (cross-wave)
    SBAR();
    __builtin_amdgcn_s_barrier();        // barrier 2: buf[cur^1] fully staged
    SBAR();
  }

  // epilogue: C/D layout col=lane&15, row=(lane>>4)*4+j; scale by dinv[row]
  int c0 = wn * 128 + fr;
  #pragma unroll
  for (int m = 0; m < 2; ++m) {
    int grb = mb + wm * 32 + m * 16 + kg * 4;
    #pragma unroll
    for (int j = 0; j < 4; ++j) {
      int gr = grb + j;
      if (gr < NND) {
        float dv = dinv[gr];
        size_t ro = (size_t)gr * ND + c0;
        #pragma unroll
        for (int n = 0; n < 8; ++n)
          hp[ro + n * 16] = f2bf(acc[m][n][j] * dv);
      }
    }
  }
}

// ---------- gather-aggregate: one wave per node ----------
__global__ void k_aggregate(const unsigned int* __restrict__ ends,
                            const unsigned int* __restrict__ deg,
                            const int* __restrict__ srcs,
                            const unsigned short* __restrict__ hp,
                            const float* __restrict__ dinv,
                            const float* __restrict__ b,
                            float* __restrict__ out) {
  int node = blockIdx.x * 4 + (threadIdx.x >> 6);
  if (node >= NND) return;
  int lane = threadIdx.x & 63;
  int q = lane * 8;

  float acc[8];
  ushort8 hs = *(const ushort8*)(hp + (size_t)node * ND + q);   // self-loop
  #pragma unroll
  for (int j = 0; j < 8; ++j) acc[j] = bf2f(hs[j]);

  unsigned int d = deg[node];
  unsigned int end = ends[node];
  unsigned int beg = end - d;
  for (unsigned int e = beg; e < end; ++e) {
    int s = srcs[e];
    ushort8 hv = *(const ushort8*)(hp + (size_t)s * ND + q);
    #pragma unroll
    for (int j = 0; j < 8; ++j) acc[j] += bf2f(hv[j]);
  }

  float dv = dinv[node];
  float4 b0 = *(const float4*)(b + q);
  float4 b1 = *(const float4*)(b + q + 4);
  float4 o0, o1;
  o0.x = acc[0] * dv + b0.x; o0.y = acc[1] * dv + b0.y;
  o0.z = acc[2] * dv + b0.z; o0.w = acc[3] * dv + b0.w;
  o1.x = acc[4] * dv + b1.x; o1.y = acc[5] * dv + b1.y;
  o1.z = acc[6] * dv + b1.z; o1.w = acc[7] * dv + b1.w;
  float* op = out + (size_t)node * ND + q;
  *(float4*)op = o0;
  *(float4*)(op + 4) = o1;
}

extern "C" void kernel_launch(void* const* d_in, const int* in_sizes, int n_in,
                              void* d_out, int out_size, void* d_ws, size_t ws_size,
                              hipStream_t stream) {
  const float* x  = (const float*)d_in[0];
  const int*   ei = (const int*)d_in[1];     // int64 in reference -> int32 in harness
  const float* W  = (const float*)d_in[2];
  const float* b  = (const float*)d_in[3];
  const float* dm = (const float*)d_in[4];
  float* out = (float*)d_out;

  char* ws = (char*)d_ws;
  unsigned short* wts  = (unsigned short*)(ws + WT_OFF);
  unsigned short* hp   = (unsigned short*)(ws + HP_OFF);
  unsigned int*   deg  = (unsigned int*)(ws + DEG_OFF);
  float*          dinv = (float*)(ws + DINV_OFF);
  unsigned int*   offs = (unsigned int*)(ws + OFFS_OFF);
  int*            srcs = (int*)(ws + SRCS_OFF);
  unsigned int*   bsum = (unsigned int*)(ws + BSUM_OFF);

  hipMemsetAsync(deg, 0, NND * sizeof(unsigned int), stream);
  hipLaunchKernelGGL(k_prep,      dim3(2587),  dim3(256), 0, stream, W, wts, ei, deg);
  hipLaunchKernelGGL(k_scan1,     dim3(391),   dim3(256), 0, stream, deg, offs, bsum, dinv);
  hipLaunchKernelGGL(k_scan2,     dim3(1),     dim3(512), 0, stream, bsum);
  hipLaunchKernelGGL(k_scan3,     dim3(391),   dim3(256), 0, stream, bsum, offs);
  hipLaunchKernelGGL(k_fill,      dim3(1563),  dim3(256), 0, stream, ei, offs, srcs);
  hipLaunchKernelGGL(k_fused,     dim3(NBLK),  dim3(512), 0, stream, x, dm, wts, dinv, hp);
  hipLaunchKernelGGL(k_aggregate, dim3(25000), dim3(256), 0, stream, offs, deg, srcs, hp, dinv, b, out);
}